// Round 6
// baseline (146.584 us; speedup 1.0000x reference)
//
#include <hip/hip_runtime.h>
#include <math.h>

// ---------------------------------------------------------------------------
// SpatialProximityHead on MI355X — round 5: 4x4-micro GEMMs (64x64 tiles,
// 512 thr, K-split-2), oprojln reverted to gemm+ln, qkt upgraded to 4x4.
// 14 dispatches.
// ---------------------------------------------------------------------------

#define NTOK 512
#define HDIM 256
#define DKH  64
#define NHEAD 4
#define TLEN 6

struct GArg { const float* A; const float* W; const float* b; float* C; };

// ---------------------------------------------------------------------------
// dist + dwraw: 8 rows per item, 512 threads.
// ---------------------------------------------------------------------------
__device__ void dist_item(const float* __restrict__ pl, float* __restrict__ dist,
                          float* __restrict__ dwraw, int item)
{
    const int t = threadIdx.x;
    const int n = item * 8 + (t >> 6);
    const int lane = t & 63;
    const float qex = pl[n * 33 + 30];
    const float qey = pl[n * 33 + 31];
    const float qez = pl[n * 33 + 32];
#pragma unroll
    for (int u = 0; u < 8; ++u) {
        const int m = lane + u * 64;
        const float dx = pl[m * 33 + 0] - qex;
        const float dy = pl[m * 33 + 1] - qey;
        const float dz = pl[m * 33 + 2] - qez;
        const float dd = sqrtf(dx * dx + dy * dy + dz * dz);
        dist[n * NTOK + m]  = dd;
        dwraw[n * NTOK + m] = 1.0f / (dd + 0.01f);
    }
}

// colsum: 64 cols per item (items 0..7), 512 threads.
__device__ void colsum_item(const float* __restrict__ dwraw,
                            float* __restrict__ inv_cs, int item, float* sm)
{
    float* red = sm;   // [8][64]
    const int t = threadIdx.x;
    const int m = item * 64 + (t & 63);
    const int ng = t >> 6;
    float s = 0.f;
    for (int n = ng * 64; n < ng * 64 + 64; ++n) s += dwraw[n * NTOK + m];
    red[ng * 64 + (t & 63)] = s;
    __syncthreads();
    if (t < 64) {
        float a = 0.f;
#pragma unroll
        for (int g = 0; g < 8; ++g) a += red[g * 64 + t];
        inv_cs[item * 64 + t] = 1.0f / a;
    }
}

// ---------------------------------------------------------------------------
// gemm64: C[64x64 tile] = A(512x256)@W(256x256)+b. 512 threads: halves split
// K (128 each, 4 chunks of 32), 4x4 micro per 256-thread half, LDS combine.
// 32 tiles per problem; problems packed 32 blocks apart on blockIdx.x.
// aux: 1 = dist items at bid>=32; 2 = colsum items at bid>=96.
// ---------------------------------------------------------------------------
__global__ __launch_bounds__(512) void gemm64(
    GArg g0, GArg g1, GArg g2, int relu, int aux,
    const float* __restrict__ pl, float* __restrict__ dist,
    float* __restrict__ dwraw, float* __restrict__ inv_cs)
{
    __shared__ __align__(16) float sm[8704];  // As[2][32][68] | Ws[2][32][68]
    const int bid = blockIdx.x;

    if (aux == 1 && bid >= 32)  { dist_item(pl, dist, dwraw, bid - 32); return; }
    if (aux == 2 && bid >= 96)  { colsum_item(dwraw, inv_cs, bid - 96, sm); return; }

    const GArg ga = (bid < 32) ? g0 : (bid < 64) ? g1 : g2;
    const int tile = bid & 31;
    const int t    = threadIdx.x;
    const int half = t >> 8;
    const int tt   = t & 255;
    const int tx   = tt & 15, ty = tt >> 4;     // cols tx*4, rows ty*4
    const int row0 = (tile >> 2) * 64;
    const int col0 = (tile & 3) * 64;

    float* As = sm + half * 2176;           // [32][68]
    float* Ws = sm + 4352 + half * 2176;    // [32][68]

    float acc[4][4] = {};

    for (int kt = 0; kt < 4; ++kt) {
        const int k0 = half * 128 + kt * 32;
#pragma unroll
        for (int j = 0; j < 2; ++j) {
            const int i  = tt * 2 + j;          // 0..511
            const int r  = i >> 3, c4 = i & 7;  // A: 64 rows x 8 f4
            const float4 av = *(const float4*)&ga.A[(row0 + r) * HDIM + k0 + c4 * 4];
            As[(c4 * 4 + 0) * 68 + r] = av.x;
            As[(c4 * 4 + 1) * 68 + r] = av.y;
            As[(c4 * 4 + 2) * 68 + r] = av.z;
            As[(c4 * 4 + 3) * 68 + r] = av.w;
            const int kr = i >> 4, cw = i & 15; // W: 32 rows x 16 f4
            *(float4*)&Ws[kr * 68 + cw * 4] =
                *(const float4*)&ga.W[(k0 + kr) * HDIM + col0 + cw * 4];
        }
        __syncthreads();
#pragma unroll
        for (int kk = 0; kk < 32; ++kk) {
            const float4 af = *(const float4*)&As[kk * 68 + ty * 4];
            const float4 wf = *(const float4*)&Ws[kk * 68 + tx * 4];
            const float a[4] = {af.x, af.y, af.z, af.w};
            const float w[4] = {wf.x, wf.y, wf.z, wf.w};
#pragma unroll
            for (int ii = 0; ii < 4; ++ii)
#pragma unroll
                for (int jj = 0; jj < 4; ++jj)
                    acc[ii][jj] += a[ii] * w[jj];
        }
        __syncthreads();
    }

    // K-half combine: half1 dumps to LDS (overlay on dead As region), half0 adds.
    float* exch = sm;   // 4096 floats
    if (half == 1) {
#pragma unroll
        for (int ii = 0; ii < 4; ++ii) {
            float4 o; o.x = acc[ii][0]; o.y = acc[ii][1];
            o.z = acc[ii][2]; o.w = acc[ii][3];
            *(float4*)&exch[(ty * 4 + ii) * 64 + tx * 4] = o;
        }
    }
    __syncthreads();
    if (half == 0) {
        float bb[4];
#pragma unroll
        for (int jj = 0; jj < 4; ++jj)
            bb[jj] = ga.b ? ga.b[col0 + tx * 4 + jj] : 0.f;
#pragma unroll
        for (int ii = 0; ii < 4; ++ii) {
            const float4 other = *(const float4*)&exch[(ty * 4 + ii) * 64 + tx * 4];
            float4 o;
            o.x = acc[ii][0] + other.x + bb[0];
            o.y = acc[ii][1] + other.y + bb[1];
            o.z = acc[ii][2] + other.z + bb[2];
            o.w = acc[ii][3] + other.w + bb[3];
            if (relu) {
                o.x = fmaxf(o.x, 0.f); o.y = fmaxf(o.y, 0.f);
                o.z = fmaxf(o.z, 0.f); o.w = fmaxf(o.w, 0.f);
            }
            *(float4*)&ga.C[(row0 + ty * 4 + ii) * HDIM + col0 + tx * 4] = o;
        }
    }
}

// ---------------------------------------------------------------------------
// qkt64: S[h][n0..+63][m0..+63] = q.k^T/8 + bias. 4x4 micro, 256 threads.
// grid (8 m-tiles, 8 n-tiles, 4 heads) = 256 blocks.
// ---------------------------------------------------------------------------
__global__ __launch_bounds__(256) void qkt_kernel(
    const float* __restrict__ q, const float* __restrict__ k,
    const float* __restrict__ dist, const float* __restrict__ dwraw,
    const float* __restrict__ inv_cs, float* __restrict__ S)
{
    __shared__ __align__(16) float Qs[64 * 68];   // [d][n]
    __shared__ __align__(16) float Ks[64 * 68];   // [d][m]

    const int h  = blockIdx.z;
    const int n0 = blockIdx.y * 64;
    const int m0 = blockIdx.x * 64;
    const int t  = threadIdx.x;

#pragma unroll
    for (int j = 0; j < 4; ++j) {
        const int i = t + j * 256;
        const int r = i >> 4, c4 = i & 15;
        const float4 qv = *(const float4*)&q[(n0 + r) * HDIM + h * DKH + c4 * 4];
        Qs[(c4 * 4 + 0) * 68 + r] = qv.x;
        Qs[(c4 * 4 + 1) * 68 + r] = qv.y;
        Qs[(c4 * 4 + 2) * 68 + r] = qv.z;
        Qs[(c4 * 4 + 3) * 68 + r] = qv.w;
        const float4 kv = *(const float4*)&k[(m0 + r) * HDIM + h * DKH + c4 * 4];
        Ks[(c4 * 4 + 0) * 68 + r] = kv.x;
        Ks[(c4 * 4 + 1) * 68 + r] = kv.y;
        Ks[(c4 * 4 + 2) * 68 + r] = kv.z;
        Ks[(c4 * 4 + 3) * 68 + r] = kv.w;
    }
    __syncthreads();

    const int tx = t & 15, ty = t >> 4;
    float acc[4][4] = {};
#pragma unroll 8
    for (int kk = 0; kk < 64; ++kk) {
        const float4 aq = *(const float4*)&Qs[kk * 68 + ty * 4];
        const float4 bk = *(const float4*)&Ks[kk * 68 + tx * 4];
        const float a[4] = {aq.x, aq.y, aq.z, aq.w};
        const float b[4] = {bk.x, bk.y, bk.z, bk.w};
#pragma unroll
        for (int ii = 0; ii < 4; ++ii)
#pragma unroll
            for (int jj = 0; jj < 4; ++jj)
                acc[ii][jj] += a[ii] * b[jj];
    }

    const int m = m0 + tx * 4;
#pragma unroll
    for (int ii = 0; ii < 4; ++ii) {
        const int n = n0 + ty * 4 + ii;
        float4 bias = {0.f, 0.f, 0.f, 0.f};
        if (h == 0) {
            const float4 dw = *(const float4*)&dwraw[n * NTOK + m];
            const float4 ic = *(const float4*)&inv_cs[m];
            bias.x = dw.x * ic.x; bias.y = dw.y * ic.y;
            bias.z = dw.z * ic.z; bias.w = dw.w * ic.w;
        } else if (h == 1) {
            const float4 dd = *(const float4*)&dist[n * NTOK + m];
            bias.x = -dd.x; bias.y = -dd.y; bias.z = -dd.z; bias.w = -dd.w;
        }
        float4 o;
        o.x = acc[ii][0] * 0.125f + bias.x;
        o.y = acc[ii][1] * 0.125f + bias.y;
        o.z = acc[ii][2] * 0.125f + bias.z;
        o.w = acc[ii][3] * 0.125f + bias.w;
        *(float4*)&S[(h * NTOK + n) * NTOK + m] = o;
    }
}

// ---------------------------------------------------------------------------
// smpv: fused softmax + full-K P@V for 8 q-rows of one head. grid (64, 4).
// ---------------------------------------------------------------------------
__global__ __launch_bounds__(256) void smpv_kernel(
    const float* __restrict__ S, const float* __restrict__ v,
    float* __restrict__ ao)
{
    __shared__ float ps[NTOK * 9];
    __shared__ float ri[8];
    __shared__ __align__(16) float exch[512];

    const int h  = blockIdx.y;
    const int n0 = blockIdx.x * 8;
    const int t  = threadIdx.x;

    {
        const int row = t >> 5, j = t & 31;
        const float* Srow = S + (h * NTOK + n0 + row) * NTOK;
        float vals[16];
        float mx = -1e30f;
#pragma unroll
        for (int u = 0; u < 16; ++u) {
            vals[u] = Srow[j + u * 32];
            mx = fmaxf(mx, vals[u]);
        }
#pragma unroll
        for (int o = 16; o; o >>= 1) mx = fmaxf(mx, __shfl_xor(mx, o, 32));
        float sum = 0.f;
#pragma unroll
        for (int u = 0; u < 16; ++u) {
            const float e = __expf(vals[u] - mx);
            vals[u] = e;
            sum += e;
        }
#pragma unroll
        for (int o = 16; o; o >>= 1) sum += __shfl_xor(sum, o, 32);
        if (j == 0) ri[row] = 1.0f / sum;
#pragma unroll
        for (int u = 0; u < 16; ++u)
            ps[(j + u * 32) * 9 + row] = vals[u];
    }
    __syncthreads();

    const int tx = t & 15, prow = (t >> 4) & 7, kh = t >> 7;
    const float* vb = v + h * DKH + tx * 4;
    float4 acc = {0.f, 0.f, 0.f, 0.f};
#pragma unroll 8
    for (int kk = kh * 256; kk < kh * 256 + 256; ++kk) {
        const float  p  = ps[kk * 9 + prow];
        const float4 vv = *(const float4*)&vb[kk * HDIM];
        acc.x += p * vv.x; acc.y += p * vv.y;
        acc.z += p * vv.z; acc.w += p * vv.w;
    }
    if (kh == 1) *(float4*)&exch[(prow * 16 + tx) * 4] = acc;
    __syncthreads();
    if (kh == 0) {
        const float4 o = *(const float4*)&exch[(prow * 16 + tx) * 4];
        const float sc = ri[prow];
        float4 r;
        r.x = (acc.x + o.x) * sc; r.y = (acc.y + o.y) * sc;
        r.z = (acc.z + o.z) * sc; r.w = (acc.w + o.w) * sc;
        *(float4*)&ao[(n0 + prow) * HDIM + h * DKH + tx * 4] = r;
    }
}

// ---------------------------------------------------------------------------
// resid_ln: x = LN(x + proj)*g + b. Row per block, 256 threads.
// ---------------------------------------------------------------------------
__global__ __launch_bounds__(256) void resid_ln(const float* __restrict__ proj,
                                                const float* __restrict__ g,
                                                const float* __restrict__ b,
                                                float* __restrict__ x)
{
    const int n = blockIdx.x, t = threadIdx.x;
    __shared__ float red[4];
    const float y = x[n * HDIM + t] + proj[n * HDIM + t];
    float s = y;
#pragma unroll
    for (int o = 32; o; o >>= 1) s += __shfl_xor(s, o);
    if ((t & 63) == 0) red[t >> 6] = s;
    __syncthreads();
    const float mean = (red[0] + red[1] + red[2] + red[3]) * (1.0f / HDIM);
    const float c = y - mean;
    float s2 = c * c;
#pragma unroll
    for (int o = 32; o; o >>= 1) s2 += __shfl_xor(s2, o);
    __syncthreads();
    if ((t & 63) == 0) red[t >> 6] = s2;
    __syncthreads();
    const float var = (red[0] + red[1] + red[2] + red[3]) * (1.0f / HDIM);
    x[n * HDIM + t] = c * rsqrtf(var + 1e-5f) * g[t] + b[t];
}

// ---------------------------------------------------------------------------
// Pair classifier: 32x32 tile, 2x2 per thread, TL copies.
// ---------------------------------------------------------------------------
__global__ __launch_bounds__(256) void pair_cls(const float* __restrict__ U1,
                                                const float* __restrict__ U2,
                                                const float* __restrict__ W2,
                                                const float* __restrict__ b2,
                                                float* __restrict__ out)
{
    __shared__ __align__(16) float u1s[32][260];
    __shared__ __align__(16) float u2s[32][260];
    __shared__ __align__(16) float w2s[256];
    const int t  = threadIdx.x;
    const int n0 = blockIdx.y * 32, m0 = blockIdx.x * 32;

    for (int i = t; i < 32 * 64; i += 256) {
        const int r = i >> 6, c4 = i & 63;
        *(float4*)&u1s[r][c4 * 4] = *(const float4*)&U1[(n0 + r) * HDIM + c4 * 4];
        *(float4*)&u2s[r][c4 * 4] = *(const float4*)&U2[(m0 + r) * HDIM + c4 * 4];
    }
    if (t < 64) *(float4*)&w2s[t * 4] = *(const float4*)&W2[t * 4];
    __syncthreads();

    const int tx = t & 15, ty = t >> 4;
    float acc[2][2] = {};
    for (int h4 = 0; h4 < 64; ++h4) {
        const float4 a0 = *(const float4*)&u1s[ty * 2][h4 * 4];
        const float4 a1 = *(const float4*)&u1s[ty * 2 + 1][h4 * 4];
        const float4 b0 = *(const float4*)&u2s[tx * 2][h4 * 4];
        const float4 b1 = *(const float4*)&u2s[tx * 2 + 1][h4 * 4];
        const float4 w  = *(const float4*)&w2s[h4 * 4];
#define RT(A, B) fmaxf((A) + (B), 0.f)
        acc[0][0] += RT(a0.x,b0.x)*w.x + RT(a0.y,b0.y)*w.y + RT(a0.z,b0.z)*w.z + RT(a0.w,b0.w)*w.w;
        acc[0][1] += RT(a0.x,b1.x)*w.x + RT(a0.y,b1.y)*w.y + RT(a0.z,b1.z)*w.z + RT(a0.w,b1.w)*w.w;
        acc[1][0] += RT(a1.x,b0.x)*w.x + RT(a1.y,b0.y)*w.y + RT(a1.z,b0.z)*w.z + RT(a1.w,b0.w)*w.w;
        acc[1][1] += RT(a1.x,b1.x)*w.x + RT(a1.y,b1.y)*w.y + RT(a1.z,b1.z)*w.z + RT(a1.w,b1.w)*w.w;
#undef RT
    }
    const float bb = b2[0];
#pragma unroll
    for (int ii = 0; ii < 2; ++ii)
#pragma unroll
        for (int jj = 0; jj < 2; ++jj) {
            const float val = acc[ii][jj] + bb;
            const int n = n0 + ty * 2 + ii;
            const int m = m0 + tx * 2 + jj;
#pragma unroll
            for (int tl = 0; tl < TLEN; ++tl)
                out[tl * NTOK * NTOK + n * NTOK + m] = val;
        }
}

// ---------------------------------------------------------------------------
extern "C" void kernel_launch(void* const* d_in, const int* in_sizes, int n_in,
                              void* d_out, int out_size, void* d_ws, size_t ws_size,
                              hipStream_t stream)
{
    const float* hs   = (const float*)d_in[0];
    const float* qf   = hs + 5 * NTOK * HDIM;
    const float* alp  = (const float*)d_in[1];
    const float* pl   = alp + 5 * NTOK * 33;
    const float* fc_W = (const float*)d_in[2];
    const float* fc_b = (const float*)d_in[3];
    const float* Wq   = (const float*)d_in[4];
    const float* bq   = (const float*)d_in[5];
    const float* Wk   = (const float*)d_in[6];
    const float* bk   = (const float*)d_in[7];
    const float* Wv   = (const float*)d_in[8];
    const float* bv   = (const float*)d_in[9];
    const float* Wo   = (const float*)d_in[10];
    const float* bo   = (const float*)d_in[11];
    const float* lng  = (const float*)d_in[12];
    const float* lnb  = (const float*)d_in[13];
    const float* m1W  = (const float*)d_in[14];
    const float* m1b  = (const float*)d_in[15];
    const float* m2W  = (const float*)d_in[16];
    const float* m2b  = (const float*)d_in[17];
    const float* cW1  = (const float*)d_in[18];
    const float* cb1  = (const float*)d_in[19];
    const float* cW2  = (const float*)d_in[20];
    const float* cb2  = (const float*)d_in[21];
    float* out = (float*)d_out;

    const int NN  = NTOK * NTOK;
    const int NH_ = NTOK * HDIM;
    float* ws     = (float*)d_ws;
    float* dist   = ws;
    float* dwraw  = ws + NN;
    float* inv_cs = ws + 2 * NN;
    float* x      = ws + 2 * NN + 512;
    float* v      = x + NH_;
    float* ao     = v + NH_;
    float* q      = ao + NH_;
    float* k      = q + NH_;
    float* S      = k + NH_;   // 4 MB

    const GArg gz = {nullptr, nullptr, nullptr, nullptr};

    // fc GEMM (blocks 0-31) + dist (blocks 32-95)
    gemm64<<<96, 512, 0, stream>>>(
        GArg{qf, fc_W, fc_b, x}, gz, gz, 1, 1, pl, dist, dwraw, inv_cs);

    for (int L = 0; L < 2; ++L) {
        const float* wq = Wq + L * HDIM * HDIM;
        const float* wk = Wk + L * HDIM * HDIM;
        const float* wv = Wv + L * HDIM * HDIM;
        const float* wo = Wo + L * HDIM * HDIM;

        // qkv GEMM x3 (blocks 0-95) + colsum (96-103, layer 0 only)
        gemm64<<<(L == 0) ? 104 : 96, 512, 0, stream>>>(
            GArg{x, wq, bq + L * HDIM, q}, GArg{x, wk, bk + L * HDIM, k},
            GArg{x, wv, bv + L * HDIM, v}, 0, (L == 0) ? 2 : 0,
            pl, dist, dwraw, inv_cs);

        qkt_kernel<<<dim3(8, 8, NHEAD), 256, 0, stream>>>(
            q, k, dist, dwraw, inv_cs, S);
        smpv_kernel<<<dim3(64, NHEAD), 256, 0, stream>>>(S, v, ao);
        // o-proj: ao @ Wo + bo -> q (q is dead after qkt)
        gemm64<<<32, 512, 0, stream>>>(
            GArg{ao, wo, bo + L * HDIM, q}, gz, gz, 0, 0,
            pl, dist, dwraw, inv_cs);
        resid_ln<<<NTOK, 256, 0, stream>>>(q, lng + L * HDIM, lnb + L * HDIM, x);
    }

    // mlp: o1 -> q, o2 -> k
    gemm64<<<64, 512, 0, stream>>>(
        GArg{x, m1W, m1b, q}, GArg{x, m2W, m2b, k}, gz, 1, 0,
        pl, dist, dwraw, inv_cs);
    // U1 = o1@cW1[:256]+cb1 -> v ; U2 = o2@cW1[256:] -> ao
    gemm64<<<64, 512, 0, stream>>>(
        GArg{q, cW1, cb1, v}, GArg{k, cW1 + HDIM * HDIM, nullptr, ao}, gz, 0, 0,
        pl, dist, dwraw, inv_cs);

    pair_cls<<<dim3(16, 16), 256, 0, stream>>>(v, ao, cW2, cb2, out);
}

// Round 7
// 113.781 us; speedup vs baseline: 1.2883x; 1.2883x over previous
//
#include <hip/hip_runtime.h>
#include <math.h>

// ---------------------------------------------------------------------------
// SpatialProximityHead on MI355X — round 6: bf16-MFMA GEMMs + qkt.
// All global tensors stay f32; f32->bf16 conversion happens during LDS
// staging inside the MFMA kernels. 14 dispatches.
// ---------------------------------------------------------------------------

#define NTOK 512
#define HDIM 256
#define DKH  64
#define NHEAD 4
#define TLEN 6
#define SA 264   // bf16 row stride, A/W panels (64 rows x 256 k)
#define SQ 72    // bf16 row stride, q/k tiles (64 rows x 64 d)

typedef __attribute__((ext_vector_type(8))) short bf16x8;
typedef __attribute__((ext_vector_type(4))) float f32x4;

struct GArg { const float* A; const float* W; const float* b; float* C; };

__device__ __forceinline__ ushort f2bf(float f)
{
    unsigned u = __builtin_bit_cast(unsigned, f);
    u += 0x7FFFu + ((u >> 16) & 1u);     // RNE
    return (ushort)(u >> 16);
}

// ---------------------------------------------------------------------------
// prep: dist/dwraw/inv_cs. 8 items, each 64 m-cols x all 512 n.
// ---------------------------------------------------------------------------
__device__ void prep_item(const float* __restrict__ pl, float* __restrict__ dist,
                          float* __restrict__ dwraw, float* __restrict__ inv_cs,
                          int item, float* smf)
{
    float* qe  = smf;           // [512][3]
    float* red = smf + 1536;    // [4][64]
    const int t = threadIdx.x;
    for (int i = t; i < 512; i += 256) {
        qe[i * 3 + 0] = pl[i * 33 + 30];
        qe[i * 3 + 1] = pl[i * 33 + 31];
        qe[i * 3 + 2] = pl[i * 33 + 32];
    }
    __syncthreads();
    const int m   = item * 64 + (t & 63);
    const int nch = t >> 6;
    const float kx = pl[m * 33 + 0], ky = pl[m * 33 + 1], kz = pl[m * 33 + 2];
    float cs = 0.f;
    for (int n = nch * 128; n < nch * 128 + 128; ++n) {
        const float dx = kx - qe[n * 3 + 0];
        const float dy = ky - qe[n * 3 + 1];
        const float dz = kz - qe[n * 3 + 2];
        const float dd = sqrtf(dx * dx + dy * dy + dz * dz);
        const float w  = 1.0f / (dd + 0.01f);
        dist[n * NTOK + m]  = dd;
        dwraw[n * NTOK + m] = w;
        cs += w;
    }
    red[nch * 64 + (t & 63)] = cs;
    __syncthreads();
    if (t < 64)
        inv_cs[item * 64 + t] =
            1.0f / (red[t] + red[64 + t] + red[128 + t] + red[192 + t]);
}

// ---------------------------------------------------------------------------
// gemm_mfma: C(512x256) = A(512x256)@W(256x256)+b via 16x16x32 bf16 MFMA.
// 64x64 tile, 256 thr (4 waves, wave w = rows w*16..+16 x all 64 cols).
// Whole-K panels staged once (bf16, converted in staging). 32 tiles/problem,
// problems packed 32 blocks apart. aux=1: blocks >=32 run prep items.
// ---------------------------------------------------------------------------
__global__ __launch_bounds__(256) void gemm_mfma(
    GArg g0, GArg g1, GArg g2, int relu, int aux, const float* __restrict__ pl,
    float* __restrict__ dist, float* __restrict__ dwraw,
    float* __restrict__ inv_cs)
{
    __shared__ __align__(16) ushort sm[2 * 64 * SA];   // As | Ws = 66 KB
    const int bid = blockIdx.x;
    if (aux && bid >= 32) { prep_item(pl, dist, dwraw, inv_cs, bid - 32, (float*)sm); return; }

    const GArg ga  = (bid < 32) ? g0 : (bid < 64) ? g1 : g2;
    const int tile = bid & 31;
    const int row0 = (tile >> 2) * 64;
    const int col0 = (tile & 3) * 64;
    const int t    = threadIdx.x;
    ushort* As = sm;             // [64 rows][SA]
    ushort* Ws = sm + 64 * SA;   // [64 cols][SA]  (W transposed: k contiguous)

    // stage A: row-major bf16
#pragma unroll
    for (int j = 0; j < 16; ++j) {
        const int i = t + j * 256;          // 0..4095 = 64 rows x 64 f4
        const int r = i >> 6, c4 = i & 63;
        const float4 av = *(const float4*)&ga.A[(row0 + r) * HDIM + c4 * 4];
        ushort4 s;
        s.x = f2bf(av.x); s.y = f2bf(av.y); s.z = f2bf(av.z); s.w = f2bf(av.w);
        *(ushort4*)&As[r * SA + c4 * 4] = s;
    }
    // stage W transposed: thread = (col-f4 cw, k-quad kq); 4 b64 stores
#pragma unroll
    for (int j = 0; j < 4; ++j) {
        const int i  = t + j * 256;         // 0..1023
        const int cw = i & 15, kq = i >> 4; // 16 col-f4 x 64 k-quads
        const float4 w0 = *(const float4*)&ga.W[(kq * 4 + 0) * HDIM + col0 + cw * 4];
        const float4 w1 = *(const float4*)&ga.W[(kq * 4 + 1) * HDIM + col0 + cw * 4];
        const float4 w2 = *(const float4*)&ga.W[(kq * 4 + 2) * HDIM + col0 + cw * 4];
        const float4 w3 = *(const float4*)&ga.W[(kq * 4 + 3) * HDIM + col0 + cw * 4];
        ushort4 s0 = {f2bf(w0.x), f2bf(w1.x), f2bf(w2.x), f2bf(w3.x)};
        ushort4 s1 = {f2bf(w0.y), f2bf(w1.y), f2bf(w2.y), f2bf(w3.y)};
        ushort4 s2 = {f2bf(w0.z), f2bf(w1.z), f2bf(w2.z), f2bf(w3.z)};
        ushort4 s3 = {f2bf(w0.w), f2bf(w1.w), f2bf(w2.w), f2bf(w3.w)};
        *(ushort4*)&Ws[(cw * 4 + 0) * SA + kq * 4] = s0;
        *(ushort4*)&Ws[(cw * 4 + 1) * SA + kq * 4] = s1;
        *(ushort4*)&Ws[(cw * 4 + 2) * SA + kq * 4] = s2;
        *(ushort4*)&Ws[(cw * 4 + 3) * SA + kq * 4] = s3;
    }
    __syncthreads();

    const int wv = t >> 6, lane = t & 63;
    const int frow = lane & 15;
    const int fk   = (lane >> 4) * 8;
    const ushort* Arow = As + (wv * 16 + frow) * SA + fk;
    const ushort* Wrow = Ws + frow * SA + fk;

    f32x4 acc[4];
#pragma unroll
    for (int j = 0; j < 4; ++j) acc[j] = (f32x4){0.f, 0.f, 0.f, 0.f};

#pragma unroll
    for (int ks = 0; ks < 8; ++ks) {
        const bf16x8 a = *(const bf16x8*)&Arow[ks * 32];
#pragma unroll
        for (int j = 0; j < 4; ++j) {
            const bf16x8 b = *(const bf16x8*)&Wrow[j * 16 * SA + ks * 32];
            acc[j] = __builtin_amdgcn_mfma_f32_16x16x32_bf16(a, b, acc[j], 0, 0, 0);
        }
    }

    const int orow = row0 + wv * 16 + (lane >> 4) * 4;
    const int ocol = col0 + (lane & 15);
#pragma unroll
    for (int j = 0; j < 4; ++j) {
        const int col = ocol + j * 16;
        const float bb = ga.b ? ga.b[col] : 0.f;
#pragma unroll
        for (int rg = 0; rg < 4; ++rg) {
            float o = acc[j][rg] + bb;
            if (relu) o = fmaxf(o, 0.f);
            ga.C[(orow + rg) * HDIM + col] = o;
        }
    }
}

// ---------------------------------------------------------------------------
// qkt_mfma: S[h] = q.k^T/8 + bias. 64x64 tile, grid (8,8,4), 256 thr.
// ---------------------------------------------------------------------------
__global__ __launch_bounds__(256) void qkt_mfma(
    const float* __restrict__ q, const float* __restrict__ k,
    const float* __restrict__ dist, const float* __restrict__ dwraw,
    const float* __restrict__ inv_cs, float* __restrict__ S)
{
    __shared__ __align__(16) ushort Qs[64 * SQ];
    __shared__ __align__(16) ushort Ks[64 * SQ];

    const int h  = blockIdx.z;
    const int n0 = blockIdx.y * 64;
    const int m0 = blockIdx.x * 64;
    const int t  = threadIdx.x;

#pragma unroll
    for (int j = 0; j < 4; ++j) {
        const int i = t + j * 256;          // 0..1023 = 64 rows x 16 f4
        const int r = i >> 4, c4 = i & 15;
        const float4 qv = *(const float4*)&q[(n0 + r) * HDIM + h * DKH + c4 * 4];
        ushort4 sq = {f2bf(qv.x), f2bf(qv.y), f2bf(qv.z), f2bf(qv.w)};
        *(ushort4*)&Qs[r * SQ + c4 * 4] = sq;
        const float4 kv = *(const float4*)&k[(m0 + r) * HDIM + h * DKH + c4 * 4];
        ushort4 sk = {f2bf(kv.x), f2bf(kv.y), f2bf(kv.z), f2bf(kv.w)};
        *(ushort4*)&Ks[r * SQ + c4 * 4] = sk;
    }
    __syncthreads();

    const int wv = t >> 6, lane = t & 63;
    const int frow = lane & 15;
    const int fk   = (lane >> 4) * 8;
    const ushort* Qrow = Qs + (wv * 16 + frow) * SQ + fk;
    const ushort* Krow = Ks + frow * SQ + fk;

    f32x4 acc[4];
#pragma unroll
    for (int j = 0; j < 4; ++j) acc[j] = (f32x4){0.f, 0.f, 0.f, 0.f};

#pragma unroll
    for (int ks = 0; ks < 2; ++ks) {
        const bf16x8 a = *(const bf16x8*)&Qrow[ks * 32];
#pragma unroll
        for (int j = 0; j < 4; ++j) {
            const bf16x8 b = *(const bf16x8*)&Krow[j * 16 * SQ + ks * 32];
            acc[j] = __builtin_amdgcn_mfma_f32_16x16x32_bf16(a, b, acc[j], 0, 0, 0);
        }
    }

    const int orow = n0 + wv * 16 + (lane >> 4) * 4;
    const int ocol = m0 + (lane & 15);
#pragma unroll
    for (int j = 0; j < 4; ++j) {
        const int m  = ocol + j * 16;
        const float ic = (h == 0) ? inv_cs[m] : 0.f;
#pragma unroll
        for (int rg = 0; rg < 4; ++rg) {
            const int n = orow + rg;
            float bias = 0.f;
            if (h == 0)      bias = dwraw[n * NTOK + m] * ic;
            else if (h == 1) bias = -dist[n * NTOK + m];
            S[(h * NTOK + n) * NTOK + m] = acc[j][rg] * 0.125f + bias;
        }
    }
}

// ---------------------------------------------------------------------------
// smpv: fused softmax + full-K P@V for 8 q-rows of one head. grid (64,4).
// Phase A: row softmax (32 thr/row), raw exp stored k-major (stride 10).
// Phase B: 4-way k-split, 2 rows/thread, V streamed from L2, LDS combine.
// ---------------------------------------------------------------------------
__global__ __launch_bounds__(256) void smpv_kernel(
    const float* __restrict__ S, const float* __restrict__ v,
    float* __restrict__ ao)
{
    __shared__ float ps[NTOK * 10];                 // 20.5 KB
    __shared__ float ri[8];
    __shared__ __align__(16) float exch[4 * 8 * 16 * 4];  // 8 KB

    const int h  = blockIdx.y;
    const int n0 = blockIdx.x * 8;
    const int t  = threadIdx.x;

    {   // Phase A
        const int row = t >> 5, j = t & 31;
        const float* Srow = S + (h * NTOK + n0 + row) * NTOK;
        float vals[16];
        float mx = -1e30f;
#pragma unroll
        for (int u = 0; u < 16; ++u) {
            vals[u] = Srow[j + u * 32];
            mx = fmaxf(mx, vals[u]);
        }
#pragma unroll
        for (int o = 16; o; o >>= 1) mx = fmaxf(mx, __shfl_xor(mx, o, 32));
        float sum = 0.f;
#pragma unroll
        for (int u = 0; u < 16; ++u) {
            const float e = __expf(vals[u] - mx);
            vals[u] = e;
            sum += e;
        }
#pragma unroll
        for (int o = 16; o; o >>= 1) sum += __shfl_xor(sum, o, 32);
        if (j == 0) ri[row] = 1.0f / sum;
#pragma unroll
        for (int u = 0; u < 16; ++u)
            ps[(j + u * 32) * 10 + row] = vals[u];
    }
    __syncthreads();

    // Phase B
    const int tx = t & 15, rp = (t >> 4) & 3, kh = t >> 6;
    const int r0 = rp * 2;
    const float* vb = v + (kh * 128) * HDIM + h * DKH + tx * 4;
    f32x4 a0 = {0.f, 0.f, 0.f, 0.f}, a1 = {0.f, 0.f, 0.f, 0.f};
#pragma unroll 8
    for (int kk = 0; kk < 128; ++kk) {
        const float4 vv = *(const float4*)&vb[kk * HDIM];
        const float2 pp = *(const float2*)&ps[(kh * 128 + kk) * 10 + r0];
        a0.x += pp.x * vv.x; a0.y += pp.x * vv.y;
        a0.z += pp.x * vv.z; a0.w += pp.x * vv.w;
        a1.x += pp.y * vv.x; a1.y += pp.y * vv.y;
        a1.z += pp.y * vv.z; a1.w += pp.y * vv.w;
    }
    if (kh > 0) {
        *(f32x4*)&exch[((kh * 8 + r0) * 16 + tx) * 4]     = a0;
        *(f32x4*)&exch[((kh * 8 + r0 + 1) * 16 + tx) * 4] = a1;
    }
    __syncthreads();
    if (kh == 0) {
#pragma unroll
        for (int kk = 1; kk < 4; ++kk) {
            const f32x4 e0 = *(const f32x4*)&exch[((kk * 8 + r0) * 16 + tx) * 4];
            const f32x4 e1 = *(const f32x4*)&exch[((kk * 8 + r0 + 1) * 16 + tx) * 4];
            a0 += e0; a1 += e1;
        }
        const float s0 = ri[r0], s1 = ri[r0 + 1];
        float4 o0, o1;
        o0.x = a0.x * s0; o0.y = a0.y * s0; o0.z = a0.z * s0; o0.w = a0.w * s0;
        o1.x = a1.x * s1; o1.y = a1.y * s1; o1.z = a1.z * s1; o1.w = a1.w * s1;
        *(float4*)&ao[(n0 + r0) * HDIM + h * DKH + tx * 4]     = o0;
        *(float4*)&ao[(n0 + r0 + 1) * HDIM + h * DKH + tx * 4] = o1;
    }
}

// ---------------------------------------------------------------------------
__global__ __launch_bounds__(256) void resid_ln(const float* __restrict__ proj,
                                                const float* __restrict__ g,
                                                const float* __restrict__ b,
                                                float* __restrict__ x)
{
    const int n = blockIdx.x, t = threadIdx.x;
    __shared__ float red[4];
    const float y = x[n * HDIM + t] + proj[n * HDIM + t];
    float s = y;
#pragma unroll
    for (int o = 32; o; o >>= 1) s += __shfl_xor(s, o);
    if ((t & 63) == 0) red[t >> 6] = s;
    __syncthreads();
    const float mean = (red[0] + red[1] + red[2] + red[3]) * (1.0f / HDIM);
    const float c = y - mean;
    float s2 = c * c;
#pragma unroll
    for (int o = 32; o; o >>= 1) s2 += __shfl_xor(s2, o);
    __syncthreads();
    if ((t & 63) == 0) red[t >> 6] = s2;
    __syncthreads();
    const float var = (red[0] + red[1] + red[2] + red[3]) * (1.0f / HDIM);
    x[n * HDIM + t] = c * rsqrtf(var + 1e-5f) * g[t] + b[t];
}

// ---------------------------------------------------------------------------
__global__ __launch_bounds__(256) void pair_cls(const float* __restrict__ U1,
                                                const float* __restrict__ U2,
                                                const float* __restrict__ W2,
                                                const float* __restrict__ b2,
                                                float* __restrict__ out)
{
    __shared__ __align__(16) float u1s[32][260];
    __shared__ __align__(16) float u2s[32][260];
    __shared__ __align__(16) float w2s[256];
    const int t  = threadIdx.x;
    const int n0 = blockIdx.y * 32, m0 = blockIdx.x * 32;

    for (int i = t; i < 32 * 64; i += 256) {
        const int r = i >> 6, c4 = i & 63;
        *(float4*)&u1s[r][c4 * 4] = *(const float4*)&U1[(n0 + r) * HDIM + c4 * 4];
        *(float4*)&u2s[r][c4 * 4] = *(const float4*)&U2[(m0 + r) * HDIM + c4 * 4];
    }
    if (t < 64) *(float4*)&w2s[t * 4] = *(const float4*)&W2[t * 4];
    __syncthreads();

    const int tx = t & 15, ty = t >> 4;
    float acc[2][2] = {};
    for (int h4 = 0; h4 < 64; ++h4) {
        const float4 a0 = *(const float4*)&u1s[ty * 2][h4 * 4];
        const float4 a1 = *(const float4*)&u1s[ty * 2 + 1][h4 * 4];
        const float4 b0 = *(const float4*)&u2s[tx * 2][h4 * 4];
        const float4 b1 = *(const float4*)&u2s[tx * 2 + 1][h4 * 4];
        const float4 w  = *(const float4*)&w2s[h4 * 4];
#define RT(A, B) fmaxf((A) + (B), 0.f)
        acc[0][0] += RT(a0.x,b0.x)*w.x + RT(a0.y,b0.y)*w.y + RT(a0.z,b0.z)*w.z + RT(a0.w,b0.w)*w.w;
        acc[0][1] += RT(a0.x,b1.x)*w.x + RT(a0.y,b1.y)*w.y + RT(a0.z,b1.z)*w.z + RT(a0.w,b1.w)*w.w;
        acc[1][0] += RT(a1.x,b0.x)*w.x + RT(a1.y,b0.y)*w.y + RT(a1.z,b0.z)*w.z + RT(a1.w,b0.w)*w.w;
        acc[1][1] += RT(a1.x,b1.x)*w.x + RT(a1.y,b1.y)*w.y + RT(a1.z,b1.z)*w.z + RT(a1.w,b1.w)*w.w;
#undef RT
    }
    const float bb = b2[0];
#pragma unroll
    for (int ii = 0; ii < 2; ++ii)
#pragma unroll
        for (int jj = 0; jj < 2; ++jj) {
            const float val = acc[ii][jj] + bb;
            const int n = n0 + ty * 2 + ii;
            const int m = m0 + tx * 2 + jj;
#pragma unroll
            for (int tl = 0; tl < TLEN; ++tl)
                out[tl * NTOK * NTOK + n * NTOK + m] = val;
        }
}

// ---------------------------------------------------------------------------
extern "C" void kernel_launch(void* const* d_in, const int* in_sizes, int n_in,
                              void* d_out, int out_size, void* d_ws, size_t ws_size,
                              hipStream_t stream)
{
    const float* hs   = (const float*)d_in[0];
    const float* qf   = hs + 5 * NTOK * HDIM;
    const float* alp  = (const float*)d_in[1];
    const float* pl   = alp + 5 * NTOK * 33;
    const float* fc_W = (const float*)d_in[2];
    const float* fc_b = (const float*)d_in[3];
    const float* Wq   = (const float*)d_in[4];
    const float* bq   = (const float*)d_in[5];
    const float* Wk   = (const float*)d_in[6];
    const float* bk   = (const float*)d_in[7];
    const float* Wv   = (const float*)d_in[8];
    const float* bv   = (const float*)d_in[9];
    const float* Wo   = (const float*)d_in[10];
    const float* bo   = (const float*)d_in[11];
    const float* lng  = (const float*)d_in[12];
    const float* lnb  = (const float*)d_in[13];
    const float* m1W  = (const float*)d_in[14];
    const float* m1b  = (const float*)d_in[15];
    const float* m2W  = (const float*)d_in[16];
    const float* m2b  = (const float*)d_in[17];
    const float* cW1  = (const float*)d_in[18];
    const float* cb1  = (const float*)d_in[19];
    const float* cW2  = (const float*)d_in[20];
    const float* cb2  = (const float*)d_in[21];
    float* out = (float*)d_out;

    const int NN  = NTOK * NTOK;
    const int NH_ = NTOK * HDIM;
    float* ws     = (float*)d_ws;
    float* dist   = ws;
    float* dwraw  = ws + NN;
    float* inv_cs = ws + 2 * NN;
    float* x      = ws + 2 * NN + 512;
    float* v      = x + NH_;
    float* ao     = v + NH_;
    float* q      = ao + NH_;
    float* k      = q + NH_;
    float* S      = k + NH_;   // 4 MB

    const GArg gz = {nullptr, nullptr, nullptr, nullptr};

    // fc GEMM (blocks 0-31) + prep dist/dwraw/inv_cs (blocks 32-39)
    gemm_mfma<<<40, 256, 0, stream>>>(
        GArg{qf, fc_W, fc_b, x}, gz, gz, 1, 1, pl, dist, dwraw, inv_cs);

    for (int L = 0; L < 2; ++L) {
        const float* wq = Wq + L * HDIM * HDIM;
        const float* wk = Wk + L * HDIM * HDIM;
        const float* wv = Wv + L * HDIM * HDIM;
        const float* wo = Wo + L * HDIM * HDIM;

        gemm_mfma<<<96, 256, 0, stream>>>(
            GArg{x, wq, bq + L * HDIM, q}, GArg{x, wk, bk + L * HDIM, k},
            GArg{x, wv, bv + L * HDIM, v}, 0, 0, pl, dist, dwraw, inv_cs);

        qkt_mfma<<<dim3(8, 8, NHEAD), 256, 0, stream>>>(
            q, k, dist, dwraw, inv_cs, S);
        smpv_kernel<<<dim3(64, NHEAD), 256, 0, stream>>>(S, v, ao);
        // o-proj: ao @ Wo + bo -> q (dead after qkt)
        gemm_mfma<<<32, 256, 0, stream>>>(
            GArg{ao, wo, bo + L * HDIM, q}, gz, gz, 0, 0, pl, dist, dwraw, inv_cs);
        resid_ln<<<NTOK, 256, 0, stream>>>(q, lng + L * HDIM, lnb + L * HDIM, x);
    }

    // mlp: o1 -> q, o2 -> k
    gemm_mfma<<<64, 256, 0, stream>>>(
        GArg{x, m1W, m1b, q}, GArg{x, m2W, m2b, k}, gz, 1, 0,
        pl, dist, dwraw, inv_cs);
    // U1 = o1@cW1[:256]+cb1 -> v ; U2 = o2@cW1[256:] -> ao
    gemm_mfma<<<64, 256, 0, stream>>>(
        GArg{q, cW1, cb1, v}, GArg{k, cW1 + HDIM * HDIM, nullptr, ao}, gz, 0, 0,
        pl, dist, dwraw, inv_cs);

    pair_cls<<<dim3(16, 16), 256, 0, stream>>>(v, ao, cW2, cb2, out);
}